// Round 4
// baseline (241.844 us; speedup 1.0000x reference)
//
#include <hip/hip_runtime.h>

// Shapes: J=64 inputs, T=64 terms, NV=4 vars, K=8 coeffs, I=64 nodes.
// under/over: [I, 2*J*T+1, NV, K] fp32 ; degrees: [I, NV] each.
namespace {
constexpr int Jc = 64, Tc = 64, NVc = 4, Ic = 64;
constexpr int F4_TERM  = 8;                        // float4 per term (32 floats)
constexpr int TERMS    = 2 * Jc * Tc + 1;          // 8193 terms per node
constexpr int NODE_F4  = TERMS * F4_TERM;          // 65544 float4 per node
constexpr int TILE_F4  = Tc * F4_TERM;             // 512 float4 per input-j tile (8 KB)
constexpr long long SIDE_F4 = (long long)Ic * NODE_F4;   // under size in f4
constexpr long long DEG_BASE_FLT = 2LL * SIDE_F4 * 4;    // 33,558,528 floats
constexpr int IG = 8;                              // nodes per block
constexpr int MAIN_BLOCKS = 2 * 2 * Jc * (Ic / IG); // 2 sides * 128 tiles * 8 groups = 2048
}

typedef float v4f __attribute__((ext_vector_type(4)));

__device__ __forceinline__ void store4(float4* p, float x, float y, float z, float w) {
    v4f v = {x, y, z, w};
    *reinterpret_cast<v4f*>(p) = v;
}

// Round 4: DIAGNOSTIC round. Body is byte-identical to the best kernel (R1,
// 143.2 us). Added: the tail block spins ~100 us after finishing its real
// work, so layer_kernel's dispatch outlasts the ~80 us poison fills and
// surfaces in the rocprof top-5 WITH its FETCH_SIZE/WRITE_SIZE counters.
// Three theories (nt-policy, write topology, read volume) are already
// falsified by dur-only deltas; FETCH/WRITE amplification vs clean 134 MB
// writes is the discriminating evidence for what remains.
__global__ __launch_bounds__(256) void layer_kernel(
    const float4* __restrict__ liu,   // layer_inputs_under  [J,T,NV,K]
    const float4* __restrict__ lio,   // layer_inputs_over   [J,T,NV,K]
    const float*  __restrict__ ud,    // under degrees [J,NV]
    const float*  __restrict__ od,    // over degrees  [J,NV]
    const float*  __restrict__ w,     // weights [I,J]
    const float*  __restrict__ bias,  // biases [I]
    float*        __restrict__ outf)  // under || over || under_deg || over_deg
{
    float4* out = reinterpret_cast<float4*>(outf);
    const int b   = blockIdx.x;
    const int tid = (int)threadIdx.x;

    if (b < MAIN_BLOCKS) {
        // Block = (side s, tile jj, i-group ig). Reads its 8 KB tile once
        // (2 float4/thread into registers), streams 16 independent stores.
        const int ig = b & 7;               // i-group [0,8)
        const int jj = (b >> 3) & 127;      // tile    [0,128): <64 = lio half, >=64 = liu
        const int s  = b >> 10;             // 0 = under, 1 = over
        const int h  = jj >> 6;
        const int j  = jj & 63;
        const int i0 = ig * IG;

        const float4* src = (h ? liu : lio) + j * TILE_F4;
        const float4 va = src[tid];
        const float4 vb = src[tid + 256];
        // var-0 coefficient row = float4 slots 0,1 of each 8-slot term
        const bool isv0 = (tid & 7) < 2;

        // under: lio*wn | liu*wp ; over: lio*wp | liu*wn  -> wn iff half==side
        float sv[IG];
        #pragma unroll
        for (int t = 0; t < IG; ++t) {
            const float wv = w[(i0 + t) * Jc + j];
            const float wp = fmaxf(wv, 0.0f);   // relu(w)
            const float wn = fminf(wv, 0.0f);   // -relu(-w)
            sv[t] = (h == s) ? wn : wp;
        }

        float4* dst = out + (long long)s * SIDE_F4 + (long long)i0 * NODE_F4
                          + (long long)jj * TILE_F4 + tid;
        #pragma unroll
        for (int t = 0; t < IG; ++t) {
            const float sc = isv0 ? sv[t] : 1.0f;
            store4(dst,       va.x * sc, va.y * sc, va.z * sc, va.w * sc);
            store4(dst + 256, vb.x * sc, vb.y * sc, vb.z * sc, vb.w * sc);
            dst += NODE_F4;
        }
    } else {
        // Tail block: bias/ones term (term 8192) for all 128 (side,node) regions + degrees.
        #pragma unroll
        for (int r = 0; r < 4; ++r) {
            const int t    = r * 256 + tid;       // [0,1024) = 128 regions * 8 f4
            const int reg  = t >> 3;
            const int i    = reg >> 1;
            const int s    = reg & 1;
            const int sub  = t & 7;               // f4 slot; var = sub>>1
            const float val = (sub < 2) ? bias[i] : 1.0f;   // var0 row = bias, rest = 1
            const long long off = (long long)s * SIDE_F4 + (long long)i * NODE_F4
                                  + (long long)(2 * Jc * Tc) * F4_TERM + sub;
            store4(out + off, val, val, val, val);
        }
        // degrees: deg[var] = max_j max(ud[j,var], od[j,var]), lane-parallel + shuffle.
        const int lane = tid & 63;                // lane = j
        float m[NVc];
        #pragma unroll
        for (int v = 0; v < NVc; ++v)
            m[v] = fmaxf(ud[lane * NVc + v], od[lane * NVc + v]);
        #pragma unroll
        for (int mask = 1; mask < 64; mask <<= 1) {
            #pragma unroll
            for (int v = 0; v < NVc; ++v)
                m[v] = fmaxf(m[v], __shfl_xor(m[v], mask, 64));
        }
        const float dv = m[tid & 3];              // tid = i*4+var
        outf[DEG_BASE_FLT + tid] = dv;            // under_deg
        outf[DEG_BASE_FLT + 256 + tid] = dv;      // over_deg

        // --- diagnostic spin: ~240k shader cycles (~100 us @ 2.4 GHz) so this
        // dispatch exceeds the ~80 us fills and shows its counters in top-5.
        const long long t0 = clock64();
        while (clock64() - t0 < 240000LL) {
            __builtin_amdgcn_s_sleep(8);
        }
    }
}

extern "C" void kernel_launch(void* const* d_in, const int* in_sizes, int n_in,
                              void* d_out, int out_size, void* d_ws, size_t ws_size,
                              hipStream_t stream) {
    const float4* liu  = (const float4*)d_in[0];
    const float4* lio  = (const float4*)d_in[1];
    const float*  ud   = (const float*)d_in[2];
    const float*  od   = (const float*)d_in[3];
    const float*  w    = (const float*)d_in[4];
    const float*  bias = (const float*)d_in[5];
    float* outf = (float*)d_out;

    layer_kernel<<<dim3(MAIN_BLOCKS + 1), dim3(256), 0, stream>>>(
        liu, lio, ud, od, w, bias, outf);
}

// Round 5
// 142.280 us; speedup vs baseline: 1.6998x; 1.6998x over previous
//
#include <hip/hip_runtime.h>

// Shapes: J=64 inputs, T=64 terms, NV=4 vars, K=8 coeffs, I=64 nodes.
// under/over: [I, 2*J*T+1, NV, K] fp32 ; degrees: [I, NV] each.
namespace {
constexpr int Jc = 64, Tc = 64, NVc = 4, Ic = 64;
constexpr int F4_TERM  = 8;                        // float4 per term (32 floats)
constexpr int TERMS    = 2 * Jc * Tc + 1;          // 8193 terms per node
constexpr int NODE_F4  = TERMS * F4_TERM;          // 65544 float4 per node (region stride)
constexpr int REG_F4   = 2 * Jc * Tc * F4_TERM;    // 65536 f4 = non-bias part of a region
constexpr int TILE_F4  = Tc * F4_TERM;             // 512 float4 per input-j tile (8 KB)
constexpr long long SIDE_F4 = (long long)Ic * NODE_F4;   // under size in f4
constexpr long long DEG_BASE_FLT = 2LL * SIDE_F4 * 4;    // 33,558,528 floats
constexpr int MAIN_BLOCKS = 2048;
}

typedef float v4f __attribute__((ext_vector_type(4)));

__device__ __forceinline__ void store4(float4* p, float x, float y, float z, float w) {
    v4f v = {x, y, z, w};
    *reinterpret_cast<v4f*>(p) = v;
}

// Round 5: fill-mimic GLOBAL write order. R1-R4 established the store stream
// is clean (WRITE=134.2 MB exact, FETCH=4.3 MB, no amplification) yet runs at
// 2.2 TB/s vs the fill's 6.5 TB/s. Remaining untested variable: machine-wide
// temporal write order. Here round r of ALL blocks writes one contiguous
// ~8.4 MB window (regions r*8 .. r*8+7), windows marching sequentially --
// the fill's exact pattern. Each thread: 1 float4 load, 16 scaled stores.
__global__ __launch_bounds__(256) void layer_kernel(
    const float4* __restrict__ liu,   // layer_inputs_under  [J,T,NV,K]
    const float4* __restrict__ lio,   // layer_inputs_over   [J,T,NV,K]
    const float*  __restrict__ ud,    // under degrees [J,NV]
    const float*  __restrict__ od,    // over degrees  [J,NV]
    const float*  __restrict__ w,     // weights [I,J]
    const float*  __restrict__ bias,  // biases [I]
    float*        __restrict__ outf)  // under || over || under_deg || over_deg
{
    float4* out = reinterpret_cast<float4*>(outf);
    const int b   = blockIdx.x;
    const int tid = (int)threadIdx.x;

    if (b < MAIN_BLOCKS) {
        // m = within-region f4 index [0,65536); fixed per thread.
        // region(r) = r*8 + (b>>8); address = region*NODE_F4 + m.
        const int breg = b >> 8;                       // [0,8)
        const int m    = ((b & 255) << 8) + tid;       // [0,65536)
        const int jj   = m >> 9;                       // tile [0,128)
        const int f4i  = m & 511;                      // f4 within tile
        const int h    = jj >> 6;                      // 0 = lio half, 1 = liu half
        const int j    = jj & 63;

        const float4 va = ((h ? liu : lio) + j * TILE_F4)[f4i];
        // var-0 coefficient row = float4 slots 0,1 of each 8-slot term
        const bool isv0 = (f4i & 7) < 2;

        #pragma unroll
        for (int r = 0; r < 16; ++r) {
            const int region = r * 8 + breg;           // [0,128) = s*64 + i
            const int s = region >> 6;
            const int i = region & 63;
            // under: lio*wn | liu*wp ; over: lio*wp | liu*wn  -> wn iff half==side
            const float wv = w[i * Jc + j];            // block-uniform -> s_load
            const float wp = fmaxf(wv, 0.0f);          // relu(w)
            const float wn = fminf(wv, 0.0f);          // -relu(-w)
            const float sc0 = (h == s) ? wn : wp;
            const float sc  = isv0 ? sc0 : 1.0f;
            float4* dst = out + (long long)region * NODE_F4 + m;
            store4(dst, va.x * sc, va.y * sc, va.z * sc, va.w * sc);
        }
    } else {
        // Tail block: bias/ones term (term 8192) for all 128 (side,node) regions + degrees.
        #pragma unroll
        for (int r = 0; r < 4; ++r) {
            const int t    = r * 256 + tid;       // [0,1024) = 128 regions * 8 f4
            const int reg  = t >> 3;
            const int i    = reg >> 1;
            const int s    = reg & 1;
            const int sub  = t & 7;               // f4 slot; var = sub>>1
            const float val = (sub < 2) ? bias[i] : 1.0f;   // var0 row = bias, rest = 1
            const long long off = (long long)s * SIDE_F4 + (long long)i * NODE_F4
                                  + (long long)REG_F4 + sub;
            store4(out + off, val, val, val, val);
        }
        // degrees: deg[var] = max_j max(ud[j,var], od[j,var]), lane-parallel + shuffle.
        const int lane = tid & 63;                // lane = j
        float mx[NVc];
        #pragma unroll
        for (int v = 0; v < NVc; ++v)
            mx[v] = fmaxf(ud[lane * NVc + v], od[lane * NVc + v]);
        #pragma unroll
        for (int mask = 1; mask < 64; mask <<= 1) {
            #pragma unroll
            for (int v = 0; v < NVc; ++v)
                mx[v] = fmaxf(mx[v], __shfl_xor(mx[v], mask, 64));
        }
        const float dv = mx[tid & 3];             // tid = i*4+var
        outf[DEG_BASE_FLT + tid] = dv;            // under_deg
        outf[DEG_BASE_FLT + 256 + tid] = dv;      // over_deg
    }
}

extern "C" void kernel_launch(void* const* d_in, const int* in_sizes, int n_in,
                              void* d_out, int out_size, void* d_ws, size_t ws_size,
                              hipStream_t stream) {
    const float4* liu  = (const float4*)d_in[0];
    const float4* lio  = (const float4*)d_in[1];
    const float*  ud   = (const float*)d_in[2];
    const float*  od   = (const float*)d_in[3];
    const float*  w    = (const float*)d_in[4];
    const float*  bias = (const float*)d_in[5];
    float* outf = (float*)d_out;

    layer_kernel<<<dim3(MAIN_BLOCKS + 1), dim3(256), 0, stream>>>(
        liu, lio, ud, od, w, bias, outf);
}